// Round 2
// 962.026 us; speedup vs baseline: 1.0357x; 1.0357x over previous
//
#include <hip/hip_runtime.h>

typedef __bf16 bf16_t;
typedef __bf16 bf16x4 __attribute__((ext_vector_type(4)));
typedef __bf16 bf16x8 __attribute__((ext_vector_type(8)));
typedef float  f32x4  __attribute__((ext_vector_type(4)));

#define HID    128
#define DIO    80
#define G4     512
#define TSTEP  512
#define BB     16
#define NBATCH 4096
#define NBLK   (NBATCH / BB)
#define HSTR   136  // LDS row stride (bf16 elems)

// Activation-domain scaling folded into the weights (preprocessing):
//   i,f,o rows scaled by -log2(e)  -> exp2(acc) = e^{-gate}
//   g rows scaled by +2*log2(e)    -> exp2(acc) = e^{2g}
// c state kept in the 2*log2(e)-scaled domain so tanh(c) = (exp2(c')-1)/(exp2(c')+1).
#define NL2E  -1.4426950408889634f
#define P2L2E  2.8853900817779268f

// Fragment layout (identical indexing for A- and B-operand of 16x16x32 bf16):
// frag tile (ntile,kt): elem[lane*8+j] = W[n=ntile*16+(lane&15)][k=kt*32+(lane>>4)*8+j]
__device__ bf16_t g_weff_frags[128 * 512];
__device__ bf16_t g_whh_frags[128 * 512];
__device__ bf16_t g_wfc_frags[20 * 512];
__device__ float  g_weff[G4 * HID];
__device__ float  g_beff[G4];
__device__ float  g_b1[G4];

// W_eff = W_hh + W_ih @ W_fc ; b_eff = b_ih + b_hh + W_ih @ b_fc ; b1 = b_ih + b_hh
// All outputs pre-scaled per-row by the activation-domain constants.
__global__ void k_weff(const float* __restrict__ W_ih, const float* __restrict__ W_hh,
                       const float* __restrict__ b_ih, const float* __restrict__ b_hh,
                       const float* __restrict__ W_fc, const float* __restrict__ b_fc) {
  int gid = blockIdx.x * blockDim.x + threadIdx.x;
  int g = gid >> 7, k = gid & 127;
  float sc = ((g >> 7) == 2) ? P2L2E : NL2E;  // gate order i,f,g,o; g-gate rows = [256,384)
  float acc = W_hh[g * HID + k];
#pragma unroll 8
  for (int d = 0; d < DIO; ++d)
    acc = fmaf(W_ih[g * DIO + d], W_fc[d * HID + k], acc);
  g_weff[g * HID + k] = acc * sc;
  if (k == 0) {
    float bb = b_ih[g] + b_hh[g];
    g_b1[g] = bb * sc;
    float be = bb;
    for (int d = 0; d < DIO; ++d) be = fmaf(W_ih[g * DIO + d], b_fc[d], be);
    g_beff[g] = be * sc;
  }
}

__global__ void k_frag(const float* __restrict__ W_hh, const float* __restrict__ W_fc) {
  int tile = blockIdx.x;  // 0..275
  int lane = threadIdx.x;
  int c = lane & 15, q = lane >> 4;
  if (tile < 128) {
    int gtile = tile >> 2, kt = tile & 3;
    int n = gtile * 16 + c;
#pragma unroll
    for (int j = 0; j < 8; ++j)
      g_weff_frags[tile * 512 + lane * 8 + j] = (bf16_t)g_weff[n * HID + kt * 32 + q * 8 + j];
  } else if (tile < 256) {
    int t2 = tile - 128;
    int gtile = t2 >> 2, kt = t2 & 3;
    int n = gtile * 16 + c;
    float sc = ((n >> 7) == 2) ? P2L2E : NL2E;
#pragma unroll
    for (int j = 0; j < 8; ++j)
      g_whh_frags[t2 * 512 + lane * 8 + j] = (bf16_t)(W_hh[n * HID + kt * 32 + q * 8 + j] * sc);
  } else {
    int t2 = tile - 256;  // 0..19 (W_fc unscaled: y output path)
    int yt = t2 >> 2, kt = t2 & 3;
    int n = yt * 16 + c;
#pragma unroll
    for (int j = 0; j < 8; ++j)
      g_wfc_frags[t2 * 512 + lane * 8 + j] = (bf16_t)W_fc[n * HID + kt * 32 + q * 8 + j];
  }
}

// 256 blocks x 512 threads (8 waves -> 2 waves/SIMD). Block owns 16 batch rows for all 512 steps.
// Transposed MFMA: gates^T = W_tile(A) x h^T(B). Wave w owns hidden cols [w*16, w*16+16) of each gate.
// C-layout: col(lane&15)=batch row, row(q*4+r)=hidden unit -> LSTM update in-register,
// h writeback = one ds_write_b64, y store = one global_store_dwordx4.
// Wave-parity s_setprio de-phases the 2 waves/SIMD so one wave's MFMA burst overlaps the
// other wave's VALU burst (they are otherwise barrier-locked in phase -> additive pipes).
__global__ __launch_bounds__(512, 2) void k_lstm(const float* __restrict__ h0,
                                                 const float* __restrict__ b_fc,
                                                 float* __restrict__ out) {
  __shared__ __align__(16) bf16_t hbuf[2][BB * HSTR];
  const int tid = threadIdx.x;
  const int lane = tid & 63;
  const int w = tid >> 6;  // 0..7
  const int c = lane & 15, q = lane >> 4;
  const int b0 = blockIdx.x * BB;

  // stage h0 -> hbuf[0]
  for (int i = tid; i < BB * HID; i += 512) {
    int r = i >> 7, k = i & 127;
    hbuf[0][r * HSTR + k] = (bf16_t)h0[(long)(b0 + r) * HID + k];
  }

  // W_fc A-fragments: waves 0..4 own y-tile w (dio cols w*16..w*16+16)
  bf16x8 Wy[4];
  f32x4  ybias;
  if (w < 5) {
#pragma unroll
    for (int kt = 0; kt < 4; ++kt)
      Wy[kt] = *(const bf16x8*)&g_wfc_frags[(w * 4 + kt) * 512 + lane * 8];
#pragma unroll
    for (int r = 0; r < 4; ++r) ybias[r] = b_fc[w * 16 + q * 4 + r];
  }

  bf16x8 Wg[4][4];  // [gate][ktile] — register/AGPR-resident
  f32x4  bias[4];   // per-r (hidden-unit) bias, pre-scaled
  auto load_wg = [&](const bf16_t* frags, const float* bsrc) {
#pragma unroll
    for (int G = 0; G < 4; ++G) {
      int gtile = G * 8 + w;
#pragma unroll
      for (int r = 0; r < 4; ++r) bias[G][r] = bsrc[gtile * 16 + q * 4 + r];
#pragma unroll
      for (int kt = 0; kt < 4; ++kt)
        Wg[G][kt] = *(const bf16x8*)&frags[(gtile * 4 + kt) * 512 + lane * 8];
    }
  };

  f32x4 cst = (f32x4){0, 0, 0, 0};  // c state (2*log2e-scaled domain), batch row c
  bf16x8 hf[4];                     // B-fragments of current h (h^T)

  __syncthreads();
#pragma unroll
  for (int kt = 0; kt < 4; ++kt)
    hf[kt] = *(const bf16x8*)&hbuf[0][c * HSTR + kt * 32 + q * 8];

  float* outp = out + (long)(b0 + c) * TSTEP * DIO + w * 16 + q * 4;

  // persistent wave-parity priority: even waves race ahead -> MFMA/VALU phases interleave
  if (((tid >> 6) & 1) == 0) __builtin_amdgcn_s_setprio(1);

  auto step = [&](int t) {
    f32x4 acc[4];
    // bias folded into first MFMA's C operand (no v_mov init)
#pragma unroll
    for (int G = 0; G < 4; ++G)
      acc[G] = __builtin_amdgcn_mfma_f32_16x16x32_bf16(Wg[G][0], hf[0], bias[G], 0, 0, 0);
#pragma unroll
    for (int kt = 1; kt < 4; ++kt)
#pragma unroll
      for (int G = 0; G < 4; ++G)
        acc[G] = __builtin_amdgcn_mfma_f32_16x16x32_bf16(Wg[G][kt], hf[kt], acc[G], 0, 0, 0);

    const int buf = t & 1;
    bf16x4 hv;
#pragma unroll
    for (int r = 0; r < 4; ++r) {
      // acc0 = -L*i, acc1 = -L*f, acc2 = 2L*g, acc3 = -L*o  (L = log2 e)
      float Ei = __builtin_amdgcn_exp2f(acc[0][r]);  // e^-i
      float Ef = __builtin_amdgcn_exp2f(acc[1][r]);  // e^-f
      float Eg = __builtin_amdgcn_exp2f(acc[2][r]);  // e^2g
      float Eo = __builtin_amdgcn_exp2f(acc[3][r]);  // e^-o
      float ai = 1.0f + Ei, af = 1.0f + Ef, ag = 1.0f + Eg;
      float P1 = ai * ag;
      float R  = __builtin_amdgcn_rcpf(P1 * af);          // 1/((1+Ei)(1+Eg)(1+Ef))
      float fs = P1 * R;                                  // sigmoid(f)
      float tg = __builtin_fmaf(Eg, P2L2E, -P2L2E);       // 2L*(Eg-1)
      float term = tg * af * R;                           // 2L*sig(i)*tanh(g)
      float cn = __builtin_fmaf(fs, cst[r], term);        // c' = 2L*c
      cst[r] = cn;
      float cc = fminf(cn, 80.0f);                        // exp2 overflow guard only
      float Ec = __builtin_amdgcn_exp2f(cc);              // e^2c
      float R2 = __builtin_amdgcn_rcpf((1.0f + Eo) * (1.0f + Ec));
      hv[r] = (bf16_t)((Ec - 1.0f) * R2);                 // sig(o)*tanh(c)
    }
    *(bf16x4*)&hbuf[buf][c * HSTR + w * 16 + q * 4] = hv;  // one ds_write_b64
    __syncthreads();  // single barrier per step (double-buffered h)
#pragma unroll
    for (int kt = 0; kt < 4; ++kt)
      hf[kt] = *(const bf16x8*)&hbuf[buf][c * HSTR + kt * 32 + q * 8];

    if (w < 5) {  // wave-uniform branch
      f32x4 ya = __builtin_amdgcn_mfma_f32_16x16x32_bf16(Wy[0], hf[0], ybias, 0, 0, 0);
#pragma unroll
      for (int kt = 1; kt < 4; ++kt)
        ya = __builtin_amdgcn_mfma_f32_16x16x32_bf16(Wy[kt], hf[kt], ya, 0, 0, 0);
      *(f32x4*)outp = ya;  // one global_store_dwordx4
      outp += DIO;
    }
  };

  // step 1: x0 == 0 => gates = h0 @ W_hh^T + (b_ih + b_hh)
  load_wg(g_whh_frags, g_b1);
  step(1);
  // steps 2..512: fused recurrence (x eliminated: W_eff = W_hh + W_ih@W_fc)
  load_wg(g_weff_frags, g_beff);
  for (int t = 2; t <= TSTEP; ++t) step(t);
}

extern "C" void kernel_launch(void* const* d_in, const int* in_sizes, int n_in,
                              void* d_out, int out_size, void* d_ws, size_t ws_size,
                              hipStream_t stream) {
  const float* h0   = (const float*)d_in[0];
  const float* W_ih = (const float*)d_in[1];
  const float* W_hh = (const float*)d_in[2];
  const float* b_ih = (const float*)d_in[3];
  const float* b_hh = (const float*)d_in[4];
  const float* W_fc = (const float*)d_in[5];
  const float* b_fc = (const float*)d_in[6];
  float* out = (float*)d_out;

  k_weff<<<256, 256, 0, stream>>>(W_ih, W_hh, b_ih, b_hh, W_fc, b_fc);
  k_frag<<<276, 64, 0, stream>>>(W_hh, W_fc);
  k_lstm<<<NBLK, 512, 0, stream>>>(h0, b_fc, out);
}

// Round 3
// 931.723 us; speedup vs baseline: 1.0694x; 1.0325x over previous
//
#include <hip/hip_runtime.h>

typedef __bf16 bf16_t;
typedef __bf16 bf16x4 __attribute__((ext_vector_type(4)));
typedef __bf16 bf16x8 __attribute__((ext_vector_type(8)));
typedef float  f32x4  __attribute__((ext_vector_type(4)));

#define HID    128
#define DIO    80
#define G4     512
#define TSTEP  512
#define BB     16
#define NBATCH 4096
#define NBLK   (NBATCH / BB)
#define HSTR   136  // LDS row stride (bf16 elems); 272B row pitch = 17*16B -> staggered banks

// Activation-domain scaling folded into the weights (preprocessing):
//   i,f,o rows scaled by -log2(e)  -> exp2(acc) = e^{-gate}
//   g rows scaled by +2*log2(e)    -> exp2(acc) = e^{2g}
// c state kept in the 2*log2(e)-scaled domain so tanh(c) = (exp2(c')-1)/(exp2(c')+1).
#define NL2E  -1.4426950408889634f
#define P2L2E  2.8853900817779268f

// Fragment layout (identical indexing for A- and B-operand of 16x16x32 bf16):
// frag tile (ntile,kt): elem[lane*8+j] = W[n=ntile*16+(lane&15)][k=kt*32+(lane>>4)*8+j]
__device__ bf16_t g_weff_frags[128 * 512];
__device__ bf16_t g_whh_frags[128 * 512];
__device__ bf16_t g_wfc_frags[20 * 512];
__device__ float  g_weff[G4 * HID];
__device__ float  g_beff[G4];
__device__ float  g_b1[G4];

// W_eff = W_hh + W_ih @ W_fc ; b_eff = b_ih + b_hh + W_ih @ b_fc ; b1 = b_ih + b_hh
// All outputs pre-scaled per-row by the activation-domain constants.
__global__ void k_weff(const float* __restrict__ W_ih, const float* __restrict__ W_hh,
                       const float* __restrict__ b_ih, const float* __restrict__ b_hh,
                       const float* __restrict__ W_fc, const float* __restrict__ b_fc) {
  int gid = blockIdx.x * blockDim.x + threadIdx.x;
  int g = gid >> 7, k = gid & 127;
  float sc = ((g >> 7) == 2) ? P2L2E : NL2E;  // gate order i,f,g,o; g-gate rows = [256,384)
  float acc = W_hh[g * HID + k];
#pragma unroll 8
  for (int d = 0; d < DIO; ++d)
    acc = fmaf(W_ih[g * DIO + d], W_fc[d * HID + k], acc);
  g_weff[g * HID + k] = acc * sc;
  if (k == 0) {
    float bb = b_ih[g] + b_hh[g];
    g_b1[g] = bb * sc;
    float be = bb;
    for (int d = 0; d < DIO; ++d) be = fmaf(W_ih[g * DIO + d], b_fc[d], be);
    g_beff[g] = be * sc;
  }
}

__global__ void k_frag(const float* __restrict__ W_hh, const float* __restrict__ W_fc) {
  int tile = blockIdx.x;  // 0..275
  int lane = threadIdx.x;
  int c = lane & 15, q = lane >> 4;
  if (tile < 128) {
    int gtile = tile >> 2, kt = tile & 3;
    int n = gtile * 16 + c;
#pragma unroll
    for (int j = 0; j < 8; ++j)
      g_weff_frags[tile * 512 + lane * 8 + j] = (bf16_t)g_weff[n * HID + kt * 32 + q * 8 + j];
  } else if (tile < 256) {
    int t2 = tile - 128;
    int gtile = t2 >> 2, kt = t2 & 3;
    int n = gtile * 16 + c;
    float sc = ((n >> 7) == 2) ? P2L2E : NL2E;
#pragma unroll
    for (int j = 0; j < 8; ++j)
      g_whh_frags[t2 * 512 + lane * 8 + j] = (bf16_t)(W_hh[n * HID + kt * 32 + q * 8 + j] * sc);
  } else {
    int t2 = tile - 256;  // 0..19 (W_fc unscaled: y output path)
    int yt = t2 >> 2, kt = t2 & 3;
    int n = yt * 16 + c;
#pragma unroll
    for (int j = 0; j < 8; ++j)
      g_wfc_frags[t2 * 512 + lane * 8 + j] = (bf16_t)W_fc[n * HID + kt * 32 + q * 8 + j];
  }
}

__device__ __forceinline__ float fexp2(float x) { return __builtin_amdgcn_exp2f(x); }
__device__ __forceinline__ float frcp(float x)  { return __builtin_amdgcn_rcpf(x); }

// 256 blocks x 512 threads (8 waves -> 2 waves/SIMD). Block owns 16 batch rows for all 512 steps.
// Transposed MFMA: gates^T = W_tile(A) x h^T(B). Wave w owns hidden cols [w*16, w*16+16) of each gate.
// C-layout: col(lane&15)=batch row, row(q*4+r)=hidden unit -> LSTM update in-register.
// y-projection DEFERRED one iteration: post-barrier we issue the 4 ds_read_b128 for the NEW h
// into the ping-pong buffer, then run 4 y-MFMAs + the global store from the OLD (register-resident)
// buffer -> the ~130cy LDS read latency is hidden under independent MFMA work instead of a stall.
__global__ __launch_bounds__(512, 2) void k_lstm(const float* __restrict__ h0,
                                                 const float* __restrict__ b_fc,
                                                 float* __restrict__ out) {
  __shared__ __align__(16) bf16_t hbuf[2][BB * HSTR];
  const int tid = threadIdx.x;
  const int lane = tid & 63;
  const int w = tid >> 6;  // 0..7
  const int c = lane & 15, q = lane >> 4;
  const int b0 = blockIdx.x * BB;

  // stage h0 -> hbuf[0]
  for (int i = tid; i < BB * HID; i += 512) {
    int r = i >> 7, k = i & 127;
    hbuf[0][r * HSTR + k] = (bf16_t)h0[(long)(b0 + r) * HID + k];
  }

  // W_fc A-fragments: waves 0..4 own y-tile w (dio cols w*16..w*16+16)
  bf16x8 Wy[4];
  f32x4  ybias;
  if (w < 5) {
#pragma unroll
    for (int kt = 0; kt < 4; ++kt)
      Wy[kt] = *(const bf16x8*)&g_wfc_frags[(w * 4 + kt) * 512 + lane * 8];
#pragma unroll
    for (int r = 0; r < 4; ++r) ybias[r] = b_fc[w * 16 + q * 4 + r];
  }

  bf16x8 Wg[4][4];  // [gate][ktile] — register/AGPR-resident
  f32x4  bias[4];   // per-r (hidden-unit) bias, pre-scaled
  auto load_wg = [&](const bf16_t* frags, const float* bsrc) {
#pragma unroll
    for (int G = 0; G < 4; ++G) {
      int gtile = G * 8 + w;
#pragma unroll
      for (int r = 0; r < 4; ++r) bias[G][r] = bsrc[gtile * 16 + q * 4 + r];
#pragma unroll
      for (int kt = 0; kt < 4; ++kt)
        Wg[G][kt] = *(const bf16x8*)&frags[(gtile * 4 + kt) * 512 + lane * 8];
    }
  };

  f32x4 cst = (f32x4){0, 0, 0, 0};  // c state (2*log2e-scaled domain), batch row c
  bf16x8 hfA[4], hfB[4];            // ping-pong B-fragments of h (h^T)

  __syncthreads();
#pragma unroll
  for (int kt = 0; kt < 4; ++kt)
    hfA[kt] = *(const bf16x8*)&hbuf[0][c * HSTR + kt * 32 + q * 8];

  float* outp = out + (long)(b0 + c) * TSTEP * DIO + w * 16 + q * 4;  // row 0

  // persistent wave-parity priority: even waves race ahead -> MFMA/VALU phases interleave
  if (((tid >> 6) & 1) == 0) __builtin_amdgcn_s_setprio(1);

// One recurrence iteration. CUR holds h(t-1) in registers; writes h(t) to hbuf[BUF];
// post-barrier: issue reads of h(t) into NXT, then (EMIT) y(h(t-1)) from CUR + store.
#define ITER(CUR, NXT, BUF, EMIT)                                                      \
  do {                                                                                 \
    f32x4 acc[4];                                                                      \
    _Pragma("unroll")                                                                  \
    for (int G = 0; G < 4; ++G)                                                        \
      acc[G] = __builtin_amdgcn_mfma_f32_16x16x32_bf16(Wg[G][0], CUR[0], bias[G], 0, 0, 0); \
    _Pragma("unroll")                                                                  \
    for (int kt = 1; kt < 4; ++kt)                                                     \
      _Pragma("unroll")                                                                \
      for (int G = 0; G < 4; ++G)                                                      \
        acc[G] = __builtin_amdgcn_mfma_f32_16x16x32_bf16(Wg[G][kt], CUR[kt], acc[G], 0, 0, 0); \
    bf16x4 hv;                                                                         \
    _Pragma("unroll")                                                                  \
    for (int r = 0; r < 4; ++r) {                                                      \
      float Ei = fexp2(acc[0][r]); /* e^-i */                                          \
      float Ef = fexp2(acc[1][r]); /* e^-f */                                          \
      float Eg = fexp2(acc[2][r]); /* e^2g */                                          \
      float Eo = fexp2(acc[3][r]); /* e^-o */                                          \
      float ai = 1.0f + Ei, af = 1.0f + Ef, ag = 1.0f + Eg;                            \
      float P1 = ai * ag;                                                              \
      float R  = frcp(P1 * af);                                                        \
      float tg = __builtin_fmaf(Eg, P2L2E, -P2L2E); /* 2L*(Eg-1) */                    \
      float m2 = tg * af;                                                              \
      float u  = __builtin_fmaf(P1, cst[r], m2);                                       \
      float cn = u * R; /* = sig(f)*c + 2L*sig(i)*tanh(g) */                           \
      cst[r] = cn;                                                                     \
      float cc = fminf(cn, 80.0f); /* exp2 overflow guard */                           \
      float Ec = fexp2(cc);        /* e^2c */                                          \
      float R2 = frcp((1.0f + Eo) * (1.0f + Ec));                                      \
      hv[r] = (bf16_t)((Ec - 1.0f) * R2); /* sig(o)*tanh(c) */                         \
    }                                                                                  \
    *(bf16x4*)&hbuf[BUF][c * HSTR + w * 16 + q * 4] = hv;                              \
    __syncthreads();                                                                   \
    _Pragma("unroll")                                                                  \
    for (int kt = 0; kt < 4; ++kt)                                                     \
      NXT[kt] = *(const bf16x8*)&hbuf[BUF][c * HSTR + kt * 32 + q * 8];                \
    if (EMIT && w < 5) { /* y from CUR (register-resident, no wait) fills read latency */ \
      f32x4 ya = __builtin_amdgcn_mfma_f32_16x16x32_bf16(Wy[0], CUR[0], ybias, 0, 0, 0); \
      _Pragma("unroll")                                                                \
      for (int kt = 1; kt < 4; ++kt)                                                   \
        ya = __builtin_amdgcn_mfma_f32_16x16x32_bf16(Wy[kt], CUR[kt], ya, 0, 0, 0);    \
      *(f32x4*)outp = ya;                                                              \
      outp += DIO;                                                                     \
    }                                                                                  \
  } while (0)

  // iter 1: x0 == 0 => gates = h0 @ W_hh^T + (b_ih + b_hh); no y emitted yet
  load_wg(g_whh_frags, g_b1);
  ITER(hfA, hfB, 1, false);
  // iters 2..512: fused recurrence (x eliminated: W_eff = W_hh + W_ih@W_fc)
  load_wg(g_weff_frags, g_beff);
  // pairs (2,3),(4,5),...,(510,511): even iter cur=hfB buf0, odd iter cur=hfA buf1
  for (int p = 0; p < 255; ++p) {
    ITER(hfB, hfA, 0, true);
    ITER(hfA, hfB, 1, true);
  }
  ITER(hfB, hfA, 0, true);  // iter 512: emits y(h511), loads h512 -> hfA

  // epilogue: y(h512) -> row 511
  if (w < 5) {
    f32x4 ya = __builtin_amdgcn_mfma_f32_16x16x32_bf16(Wy[0], hfA[0], ybias, 0, 0, 0);
#pragma unroll
    for (int kt = 1; kt < 4; ++kt)
      ya = __builtin_amdgcn_mfma_f32_16x16x32_bf16(Wy[kt], hfA[kt], ya, 0, 0, 0);
    *(f32x4*)outp = ya;
  }
#undef ITER
}

extern "C" void kernel_launch(void* const* d_in, const int* in_sizes, int n_in,
                              void* d_out, int out_size, void* d_ws, size_t ws_size,
                              hipStream_t stream) {
  const float* h0   = (const float*)d_in[0];
  const float* W_ih = (const float*)d_in[1];
  const float* W_hh = (const float*)d_in[2];
  const float* b_ih = (const float*)d_in[3];
  const float* b_hh = (const float*)d_in[4];
  const float* W_fc = (const float*)d_in[5];
  const float* b_fc = (const float*)d_in[6];
  float* out = (float*)d_out;

  k_weff<<<256, 256, 0, stream>>>(W_ih, W_hh, b_ih, b_hh, W_fc, b_fc);
  k_frag<<<276, 64, 0, stream>>>(W_hh, W_fc);
  k_lstm<<<NBLK, 512, 0, stream>>>(h0, b_fc, out);
}